// Round 1
// baseline (1709.572 us; speedup 1.0000x reference)
//
#include <hip/hip_runtime.h>
#include <math.h>

// Problem constants (Qwen2 block, B=8 L=16 E=2048 S0=4096 F=5632 H=16 HKV=2 D=128)
#define BB 8
#define LL 16
#define EE 2048
#define S0C 4096
#define FF 5632
#define HH 16
#define HKV 2
#define DD 128
#define GG 8
#define MM 128          // B*L tokens
#define STOT 4112       // S0C + LL

// ---------------- RMSNorm: one block per row (E=2048, 256 thr * 8 elems) ----------
__global__ __launch_bounds__(256) void rmsnorm_kernel(const float* __restrict__ x,
                                                      const float* __restrict__ w,
                                                      float* __restrict__ out) {
    int row = blockIdx.x;
    int t = threadIdx.x;
    const float4* xr = (const float4*)(x + row * EE);
    float4 a = xr[t];
    float4 b = xr[t + 256];
    float ss = a.x*a.x + a.y*a.y + a.z*a.z + a.w*a.w
             + b.x*b.x + b.y*b.y + b.z*b.z + b.w*b.w;
    #pragma unroll
    for (int o = 32; o > 0; o >>= 1) ss += __shfl_down(ss, o);
    __shared__ float red[4];
    if ((t & 63) == 0) red[t >> 6] = ss;
    __syncthreads();
    float tot = red[0] + red[1] + red[2] + red[3];
    float inv = rsqrtf(tot * (1.0f / (float)EE) + 1e-6f);
    const float4* wr = (const float4*)w;
    float4 w0 = wr[t], w1 = wr[t + 256];
    float4 o0, o1;
    o0.x = a.x*inv*w0.x; o0.y = a.y*inv*w0.y; o0.z = a.z*inv*w0.z; o0.w = a.w*inv*w0.w;
    o1.x = b.x*inv*w1.x; o1.y = b.y*inv*w1.y; o1.z = b.z*inv*w1.z; o1.w = b.w*inv*w1.w;
    float4* orow = (float4*)(out + row * EE);
    orow[t] = o0;
    orow[t + 256] = o1;
}

// ---------------- Generic fp32 GEMM body: C[64 x 16] tile, BK=32, 256 threads ------
// C = A[M,K] @ W[N,K]^T (+bias) (+res). A pre-offset to m0 row, W pre-offset to n0 row,
// C/res pre-offset to (m0, n0).
__device__ __forceinline__ void gemm_body(const float* __restrict__ A, int K,
                                          const float* __restrict__ W,
                                          const float* __restrict__ bias,
                                          const float* __restrict__ res,
                                          float* __restrict__ C, int ldc) {
    __shared__ float As[32][68];   // [k][m], pad 68 (mult of 4 for b128 align)
    __shared__ float Ws[32][17];   // [k][n], pad 17
    int t = threadIdx.x;
    int nl = t & 15;
    int mb = (t >> 4) << 2;        // 4 rows per thread
    float acc0 = 0.f, acc1 = 0.f, acc2 = 0.f, acc3 = 0.f;
    for (int k0 = 0; k0 < K; k0 += 32) {
        #pragma unroll
        for (int i = 0; i < 2; i++) {
            int idx = t + 256 * i;
            int m = idx >> 3;
            int kc = (idx & 7) << 2;
            float4 a4 = *(const float4*)(A + m * K + k0 + kc);
            As[kc + 0][m] = a4.x; As[kc + 1][m] = a4.y;
            As[kc + 2][m] = a4.z; As[kc + 3][m] = a4.w;
        }
        if (t < 128) {
            int n = t >> 3;
            int kc = (t & 7) << 2;
            float4 w4 = *(const float4*)(W + n * K + k0 + kc);
            Ws[kc + 0][n] = w4.x; Ws[kc + 1][n] = w4.y;
            Ws[kc + 2][n] = w4.z; Ws[kc + 3][n] = w4.w;
        }
        __syncthreads();
        #pragma unroll
        for (int kk = 0; kk < 32; kk++) {
            float4 a = *(const float4*)&As[kk][mb];
            float wv = Ws[kk][nl];
            acc0 += a.x * wv; acc1 += a.y * wv;
            acc2 += a.z * wv; acc3 += a.w * wv;
        }
        __syncthreads();
    }
    float bb = bias ? bias[nl] : 0.f;
    float r0 = res ? res[(mb + 0) * ldc + nl] : 0.f;
    float r1 = res ? res[(mb + 1) * ldc + nl] : 0.f;
    float r2 = res ? res[(mb + 2) * ldc + nl] : 0.f;
    float r3 = res ? res[(mb + 3) * ldc + nl] : 0.f;
    C[(mb + 0) * ldc + nl] = acc0 + bb + r0;
    C[(mb + 1) * ldc + nl] = acc1 + bb + r1;
    C[(mb + 2) * ldc + nl] = acc2 + bb + r2;
    C[(mb + 3) * ldc + nl] = acc3 + bb + r3;
}

__global__ __launch_bounds__(256) void gemm_kernel(const float* __restrict__ A,
                                                   const float* __restrict__ W,
                                                   const float* __restrict__ bias,
                                                   const float* __restrict__ res,
                                                   float* __restrict__ C, int K, int ldc) {
    int n0 = blockIdx.x * 16;
    int m0 = blockIdx.y * 64;
    gemm_body(A + (size_t)m0 * K, K, W + (size_t)n0 * K,
              bias ? bias + n0 : nullptr,
              res ? res + (size_t)m0 * ldc + n0 : nullptr,
              C + (size_t)m0 * ldc + n0, ldc);
}

// Combined QKV: columns [0,2048)->q(wq,bq), [2048,2304)->k(wk,bk), [2304,2560)->v(wv,bv)
__global__ __launch_bounds__(256) void gemm_qkv_kernel(const float* __restrict__ xn,
                                                       const float* __restrict__ wq,
                                                       const float* __restrict__ wk,
                                                       const float* __restrict__ wv,
                                                       const float* __restrict__ bq,
                                                       const float* __restrict__ bk,
                                                       const float* __restrict__ bv,
                                                       float* __restrict__ q,
                                                       float* __restrict__ k,
                                                       float* __restrict__ v) {
    int n0 = blockIdx.x * 16;
    int m0 = blockIdx.y * 64;
    const float* W; const float* bias; float* C; int ldc; int nl;
    if (n0 < 2048)      { W = wq; bias = bq; C = q; ldc = 2048; nl = n0; }
    else if (n0 < 2304) { W = wk; bias = bk; C = k; ldc = 256;  nl = n0 - 2048; }
    else                { W = wv; bias = bv; C = v; ldc = 256;  nl = n0 - 2304; }
    gemm_body(xn + (size_t)m0 * EE, EE, W + (size_t)nl * EE, bias + nl,
              nullptr, C + (size_t)m0 * ldc + nl, ldc);
}

// ---------------- RoPE in-place on q (128x2048 as tokens x [h][128]) and k (128x256) ----
__global__ __launch_bounds__(256) void rope_kernel(float* __restrict__ q,
                                                   float* __restrict__ k,
                                                   const int* __restrict__ offp) {
    int t = blockIdx.x * 256 + threadIdx.x;    // 147456 total
    int off = offp[0];
    float* ptr; int dh; int l;
    if (t < 131072) {                           // q: 128 tok * 16 heads * 64
        int token = t >> 10;
        int rem = t & 1023;
        int hh = rem >> 6;
        dh = rem & 63;
        ptr = q + token * EE + hh * DD;
        l = token & 15;
    } else {                                    // k: 128 tok * 2 kvheads * 64
        int t2 = t - 131072;
        int token = t2 >> 7;
        int rem = t2 & 127;
        int hh = rem >> 6;
        dh = rem & 63;
        ptr = k + token * (HKV * DD) + hh * DD;
        l = token & 15;
    }
    float pos = (float)(off + l);
    // inv_freq = 10000^(-dh/64) = exp2(-dh * log2(10000)/64)
    float inv = exp2f(-(float)dh * (13.287712379549449f / 64.0f));
    float ang = pos * inv;
    float s, c;
    sincosf(ang, &s, &c);
    float x0 = ptr[dh], x1 = ptr[dh + 64];
    ptr[dh]      = x0 * c - x1 * s;
    ptr[dh + 64] = x1 * c + x0 * s;
}

// ---------------- Flash attention: one block per (b, h); CS=32 chunked over S=4112 ----
#define CS 32
__global__ __launch_bounds__(256) void attn_kernel(const float* __restrict__ q,
                                                   const float* __restrict__ kn,
                                                   const float* __restrict__ vn,
                                                   const float* __restrict__ ck,
                                                   const float* __restrict__ cv,
                                                   const int* __restrict__ offp,
                                                   float* __restrict__ o) {
    __shared__ float Qs[16][132];
    __shared__ float Ks[CS][132];
    __shared__ float Vs[CS][128];
    __shared__ float Ss[16][33];
    __shared__ float mrow[16], lrow[16], arow[16];

    int t = threadIdx.x;
    int b = blockIdx.x >> 4;
    int h = blockIdx.x & 15;
    int kv = h >> 3;
    int off = offp[0];

    // stage Q tile (16 x 128)
    #pragma unroll
    for (int i = 0; i < 2; i++) {
        int idx = t + 256 * i;
        int r = idx >> 5;
        int kk = (idx & 31) << 2;
        float4 v4 = *(const float4*)(q + (size_t)(b * 16 + r) * EE + h * DD + kk);
        *(float4*)&Qs[r][kk] = v4;
    }
    if (t < 16) { mrow[t] = -3.0e38f; lrow[t] = 0.f; }

    float O0[8];
    #pragma unroll
    for (int j = 0; j < 8; j++) O0[j] = 0.f;

    int rr = t & 15;
    int d0 = (t >> 4) * 8;
    int sc = t >> 3;            // score col 0..31
    int r0 = (t & 7) * 2;       // score rows r0, r0+1
    const float scl = 0.08838834764831845f;

    const float* ckb = ck + ((size_t)(b * HKV + kv)) * S0C * DD;
    const float* cvb = cv + ((size_t)(b * HKV + kv)) * S0C * DD;
    const float* knb = kn + (size_t)(b * 16) * (HKV * DD) + kv * DD;
    const float* vnb = vn + (size_t)(b * 16) * (HKV * DD) + kv * DD;

    for (int s0 = 0; s0 < STOT; s0 += CS) {
        int cs = min(CS, STOT - s0);
        __syncthreads();   // previous PV done before restaging
        // stage K/V chunk
        #pragma unroll
        for (int i = 0; i < (CS * 32) / 256; i++) {
            int idx = t + 256 * i;
            if (idx < cs * 32) {
                int row = idx >> 5;
                int kk = (idx & 31) << 2;
                int sg = s0 + row;
                const float* kp; const float* vp;
                if (sg < S0C) { kp = ckb + (size_t)sg * DD; vp = cvb + (size_t)sg * DD; }
                else { kp = knb + (size_t)(sg - S0C) * (HKV * DD);
                       vp = vnb + (size_t)(sg - S0C) * (HKV * DD); }
                *(float4*)&Ks[row][kk] = *(const float4*)(kp + kk);
                *(float4*)&Vs[row][kk] = *(const float4*)(vp + kk);
            }
        }
        __syncthreads();
        // scores: 2 rows per thread
        if (sc < cs) {
            float da = 0.f, db = 0.f;
            #pragma unroll
            for (int kk = 0; kk < 32; kk++) {
                float4 k4 = *(const float4*)&Ks[sc][kk << 2];
                float4 q0 = *(const float4*)&Qs[r0][kk << 2];
                float4 q1 = *(const float4*)&Qs[r0 + 1][kk << 2];
                da += q0.x*k4.x + q0.y*k4.y + q0.z*k4.z + q0.w*k4.w;
                db += q1.x*k4.x + q1.y*k4.y + q1.z*k4.z + q1.w*k4.w;
            }
            int sg = s0 + sc;
            Ss[r0][sc]     = (sg <= off + r0)     ? da * scl : -1e30f;
            Ss[r0 + 1][sc] = (sg <= off + r0 + 1) ? db * scl : -1e30f;
        }
        __syncthreads();
        // online softmax update (16 rows, 16 threads)
        if (t < 16) {
            float mold = mrow[t];
            float mx = mold;
            for (int c = 0; c < cs; c++) mx = fmaxf(mx, Ss[t][c]);
            float alpha = __expf(mold - mx);
            float sum = 0.f;
            for (int c = 0; c < cs; c++) {
                float p = __expf(Ss[t][c] - mx);
                Ss[t][c] = p;
                sum += p;
            }
            mrow[t] = mx;
            lrow[t] = lrow[t] * alpha + sum;
            arow[t] = alpha;
        }
        __syncthreads();
        // PV accumulate
        float alpha = arow[rr];
        #pragma unroll
        for (int j = 0; j < 8; j++) O0[j] *= alpha;
        for (int c = 0; c < cs; c++) {
            float p = Ss[rr][c];
            float4 v0 = *(const float4*)&Vs[c][d0];
            float4 v1 = *(const float4*)&Vs[c][d0 + 4];
            O0[0] += p * v0.x; O0[1] += p * v0.y; O0[2] += p * v0.z; O0[3] += p * v0.w;
            O0[4] += p * v1.x; O0[5] += p * v1.y; O0[6] += p * v1.z; O0[7] += p * v1.w;
        }
    }
    float linv = 1.0f / lrow[rr];
    #pragma unroll
    for (int j = 0; j < 8; j++)
        o[(size_t)(b * 16 + rr) * EE + h * DD + d0 + j] = O0[j] * linv;
}

// ---------------- silu(gate) * up, in-place into gate ----------------
__global__ __launch_bounds__(256) void silu_mul_kernel(float* __restrict__ g,
                                                       const float* __restrict__ u) {
    int i = blockIdx.x * 256 + threadIdx.x;   // 720896 total
    float gv = g[i];
    float uv = u[i];
    g[i] = gv / (1.0f + __expf(-gv)) * uv;
}

// ---------------- launch ----------------
extern "C" void kernel_launch(void* const* d_in, const int* in_sizes, int n_in,
                              void* d_out, int out_size, void* d_ws, size_t ws_size,
                              hipStream_t stream) {
    const float* x        = (const float*)d_in[0];
    const float* cache_k  = (const float*)d_in[1];
    const float* cache_v  = (const float*)d_in[2];
    const float* wq       = (const float*)d_in[3];
    const float* wk       = (const float*)d_in[4];
    const float* wv       = (const float*)d_in[5];
    const float* wo       = (const float*)d_in[6];
    const float* bq       = (const float*)d_in[7];
    const float* bk       = (const float*)d_in[8];
    const float* bv       = (const float*)d_in[9];
    const float* w_gate   = (const float*)d_in[10];
    const float* w_up     = (const float*)d_in[11];
    const float* w_down   = (const float*)d_in[12];
    const float* w_in_ln  = (const float*)d_in[13];
    const float* w_post_ln= (const float*)d_in[14];
    const int*   offp     = (const int*)d_in[15];
    float* out = (float*)d_out;

    float* ws = (float*)d_ws;
    // workspace layout (floats)
    float* xn   = ws;                      // 262144 (also reused as hn)
    float* qb   = ws + 262144;             // 262144
    float* kb   = ws + 524288;             // 32768
    float* vb   = ws + 557056;             // 32768
    float* ob   = ws + 589824;             // 262144
    float* hb   = ws + 851968;             // 262144
    float* gb   = ws + 1114112;            // 720896
    float* ub   = ws + 1835008;            // 720896  (total 2555904 floats = 10.2 MB)

    // 1) input RMSNorm
    rmsnorm_kernel<<<MM, 256, 0, stream>>>(x, w_in_ln, xn);
    // 2) QKV projection (fused over N = 2048+256+256 = 2560)
    gemm_qkv_kernel<<<dim3(160, 2), 256, 0, stream>>>(xn, wq, wk, wv, bq, bk, bv, qb, kb, vb);
    // 3) RoPE on q and k
    rope_kernel<<<576, 256, 0, stream>>>(qb, kb, offp);
    // 4) attention over cache + new tokens
    attn_kernel<<<BB * HH, 256, 0, stream>>>(qb, kb, vb, cache_k, cache_v, offp, ob);
    // 5) O projection + residual -> h
    gemm_kernel<<<dim3(128, 2), 256, 0, stream>>>(ob, wo, nullptr, x, hb, 2048, 2048);
    // 6) post RMSNorm -> hn (reuse xn)
    rmsnorm_kernel<<<MM, 256, 0, stream>>>(hb, w_post_ln, xn);
    // 7) gate & up
    gemm_kernel<<<dim3(352, 2), 256, 0, stream>>>(xn, w_gate, nullptr, nullptr, gb, 2048, 5632);
    gemm_kernel<<<dim3(352, 2), 256, 0, stream>>>(xn, w_up,   nullptr, nullptr, ub, 2048, 5632);
    // 8) silu(gate)*up in-place
    silu_mul_kernel<<<2816, 256, 0, stream>>>(gb, ub);
    // 9) down projection + residual h -> out
    gemm_kernel<<<dim3(128, 2), 256, 0, stream>>>(gb, w_down, nullptr, hb, out, 5632, 2048);
}

// Round 2
// 678.704 us; speedup vs baseline: 2.5189x; 2.5189x over previous
//
#include <hip/hip_runtime.h>
#include <math.h>

// Qwen2 block: B=8 L=16 E=2048 S0=4096 F=5632 H=16 HKV=2 D=128
#define MM 128
#define EE 2048
#define FF 5632
#define S0C 4096
#define STOT 4112
#define NSPLIT 32

typedef float f32x4 __attribute__((ext_vector_type(4)));
typedef short s16x8 __attribute__((ext_vector_type(8)));

#define MFMA16(a, b, c) __builtin_amdgcn_mfma_f32_16x16x32_bf16(a, b, c, 0, 0, 0)

__device__ __forceinline__ unsigned short f2bfu(float f) {
    unsigned u = __float_as_uint(f);
    u += 0x7fffu + ((u >> 16) & 1u);
    return (unsigned short)(u >> 16);
}
__device__ __forceinline__ unsigned pk2(float lo, float hi) {
    return (unsigned)f2bfu(lo) | ((unsigned)f2bfu(hi) << 16);
}
__device__ __forceinline__ float bf2f(unsigned short u) {
    return __uint_as_float(((unsigned)u) << 16);
}

// ---------------- RMSNorm ----------------
__global__ __launch_bounds__(256) void rmsnorm_kernel(const float* __restrict__ x,
                                                      const float* __restrict__ w,
                                                      float* __restrict__ out) {
    int row = blockIdx.x;
    int t = threadIdx.x;
    const float4* xr = (const float4*)(x + row * EE);
    float4 a = xr[t];
    float4 b = xr[t + 256];
    float ss = a.x*a.x + a.y*a.y + a.z*a.z + a.w*a.w
             + b.x*b.x + b.y*b.y + b.z*b.z + b.w*b.w;
    #pragma unroll
    for (int o = 32; o > 0; o >>= 1) ss += __shfl_down(ss, o);
    __shared__ float red[4];
    if ((t & 63) == 0) red[t >> 6] = ss;
    __syncthreads();
    float tot = red[0] + red[1] + red[2] + red[3];
    float inv = rsqrtf(tot * (1.0f / (float)EE) + 1e-6f);
    const float4* wr = (const float4*)w;
    float4 w0 = wr[t], w1 = wr[t + 256];
    float4 o0, o1;
    o0.x = a.x*inv*w0.x; o0.y = a.y*inv*w0.y; o0.z = a.z*inv*w0.z; o0.w = a.w*inv*w0.w;
    o1.x = b.x*inv*w1.x; o1.y = b.y*inv*w1.y; o1.z = b.z*inv*w1.z; o1.w = b.w*inv*w1.w;
    float4* orow = (float4*)(out + row * EE);
    orow[t] = o0;
    orow[t + 256] = o1;
}

// ---------------- bf16 MFMA GEMM body: C[128 x 16] strip, BK=32 ----------------
// C[m][n] = sum_k A[m][k] * W[n][k]  (+bias[n]) (+res[m][n])
// W pre-offset to n-strip, bias/res/C pre-offset likewise.
__device__ __forceinline__ void gemm16_body(const float* __restrict__ A, int K,
                                            const float* __restrict__ W,
                                            const float* __restrict__ bias,
                                            const float* __restrict__ res,
                                            float* __restrict__ C, int ldc) {
    __shared__ __align__(16) short As[128 * 40];   // row stride 40 bf16 (80 B)
    __shared__ __align__(16) short Bs[16 * 40];
    int t = threadIdx.x;
    int wv = t >> 6, lane = t & 63, quad = lane >> 4, l15 = lane & 15;
    f32x4 acc0 = {0.f, 0.f, 0.f, 0.f};
    f32x4 acc1 = {0.f, 0.f, 0.f, 0.f};
    float bv = bias ? bias[l15] : 0.f;
    int arow = t >> 1, ahalf = t & 1;
    const float* ap = A + (size_t)arow * K + ahalf * 16;
    unsigned* Asu = (unsigned*)As;
    unsigned* Bsu = (unsigned*)Bs;
    for (int k0 = 0; k0 < K; k0 += 32) {
        float4 a0 = *(const float4*)(ap + k0);
        float4 a1 = *(const float4*)(ap + k0 + 4);
        float4 a2 = *(const float4*)(ap + k0 + 8);
        float4 a3 = *(const float4*)(ap + k0 + 12);
        int ai = arow * 20 + ahalf * 8;
        *(uint4*)(Asu + ai)     = make_uint4(pk2(a0.x,a0.y), pk2(a0.z,a0.w), pk2(a1.x,a1.y), pk2(a1.z,a1.w));
        *(uint4*)(Asu + ai + 4) = make_uint4(pk2(a2.x,a2.y), pk2(a2.z,a2.w), pk2(a3.x,a3.y), pk2(a3.z,a3.w));
        if (t < 32) {
            const float* wp = W + (size_t)(t >> 1) * K + (t & 1) * 16 + k0;
            float4 b0 = *(const float4*)(wp);
            float4 b1 = *(const float4*)(wp + 4);
            float4 b2 = *(const float4*)(wp + 8);
            float4 b3 = *(const float4*)(wp + 12);
            int bi = (t >> 1) * 20 + (t & 1) * 8;
            *(uint4*)(Bsu + bi)     = make_uint4(pk2(b0.x,b0.y), pk2(b0.z,b0.w), pk2(b1.x,b1.y), pk2(b1.z,b1.w));
            *(uint4*)(Bsu + bi + 4) = make_uint4(pk2(b2.x,b2.y), pk2(b2.z,b2.w), pk2(b3.x,b3.y), pk2(b3.z,b3.w));
        }
        __syncthreads();
        s16x8 af0 = *(const s16x8*)(As + (wv * 32 + l15) * 40 + quad * 8);
        s16x8 af1 = *(const s16x8*)(As + (wv * 32 + 16 + l15) * 40 + quad * 8);
        s16x8 bf  = *(const s16x8*)(Bs + l15 * 40 + quad * 8);
        acc0 = MFMA16(af0, bf, acc0);
        acc1 = MFMA16(af1, bf, acc1);
        __syncthreads();
    }
    #pragma unroll
    for (int r = 0; r < 4; r++) {
        int row0 = wv * 32 + quad * 4 + r;
        int row1 = row0 + 16;
        float v0 = acc0[r] + bv;
        float v1 = acc1[r] + bv;
        if (res) {
            v0 += res[(size_t)row0 * ldc + l15];
            v1 += res[(size_t)row1 * ldc + l15];
        }
        C[(size_t)row0 * ldc + l15] = v0;
        C[(size_t)row1 * ldc + l15] = v1;
    }
}

__global__ __launch_bounds__(256) void gemm16_kernel(const float* __restrict__ A,
                                                     const float* __restrict__ W,
                                                     const float* __restrict__ bias,
                                                     const float* __restrict__ res,
                                                     float* __restrict__ C, int K, int ldc) {
    int n0 = blockIdx.x * 16;
    gemm16_body(A, K, W + (size_t)n0 * K,
                bias ? bias + n0 : nullptr,
                res ? res + n0 : nullptr,
                C + n0, ldc);
}

// QKV: n strips [0,2048)->q, [2048,2304)->k, [2304,2560)->v
__global__ __launch_bounds__(256) void qkv_kernel(const float* __restrict__ xn,
                                                  const float* __restrict__ wq,
                                                  const float* __restrict__ wk,
                                                  const float* __restrict__ wv,
                                                  const float* __restrict__ bq,
                                                  const float* __restrict__ bk,
                                                  const float* __restrict__ bv,
                                                  float* __restrict__ q,
                                                  float* __restrict__ k,
                                                  float* __restrict__ v) {
    int n0 = blockIdx.x * 16;
    if (n0 < 2048) {
        gemm16_body(xn, EE, wq + (size_t)n0 * EE, bq + n0, nullptr, q + n0, 2048);
    } else if (n0 < 2304) {
        int nl = n0 - 2048;
        gemm16_body(xn, EE, wk + (size_t)nl * EE, bk + nl, nullptr, k + nl, 256);
    } else {
        int nl = n0 - 2304;
        gemm16_body(xn, EE, wv + (size_t)nl * EE, bv + nl, nullptr, v + nl, 256);
    }
}

// Gate+Up fused with silu(g)*u epilogue
__global__ __launch_bounds__(256) void gateup_kernel(const float* __restrict__ A,
                                                     const float* __restrict__ Wg,
                                                     const float* __restrict__ Wu,
                                                     float* __restrict__ C) {
    __shared__ __align__(16) short As[128 * 40];
    __shared__ __align__(16) short Bg[16 * 40];
    __shared__ __align__(16) short Bu[16 * 40];
    int t = threadIdx.x;
    int wv = t >> 6, lane = t & 63, quad = lane >> 4, l15 = lane & 15;
    int n0 = blockIdx.x * 16;
    f32x4 ag0 = {0.f,0.f,0.f,0.f}, ag1 = ag0, au0 = ag0, au1 = ag0;
    int arow = t >> 1, ahalf = t & 1;
    const float* ap = A + (size_t)arow * EE + ahalf * 16;
    unsigned* Asu = (unsigned*)As;
    for (int k0 = 0; k0 < EE; k0 += 32) {
        float4 a0 = *(const float4*)(ap + k0);
        float4 a1 = *(const float4*)(ap + k0 + 4);
        float4 a2 = *(const float4*)(ap + k0 + 8);
        float4 a3 = *(const float4*)(ap + k0 + 12);
        int ai = arow * 20 + ahalf * 8;
        *(uint4*)(Asu + ai)     = make_uint4(pk2(a0.x,a0.y), pk2(a0.z,a0.w), pk2(a1.x,a1.y), pk2(a1.z,a1.w));
        *(uint4*)(Asu + ai + 4) = make_uint4(pk2(a2.x,a2.y), pk2(a2.z,a2.w), pk2(a3.x,a3.y), pk2(a3.z,a3.w));
        if (t < 64) {
            int mat = t >> 5, tt = t & 31;
            int row = tt >> 1, half = tt & 1;
            const float* wp = (mat ? Wu : Wg) + (size_t)(n0 + row) * EE + half * 16 + k0;
            float4 b0 = *(const float4*)(wp);
            float4 b1 = *(const float4*)(wp + 4);
            float4 b2 = *(const float4*)(wp + 8);
            float4 b3 = *(const float4*)(wp + 12);
            unsigned* Bp = (unsigned*)(mat ? Bu : Bg);
            int bi = row * 20 + half * 8;
            *(uint4*)(Bp + bi)     = make_uint4(pk2(b0.x,b0.y), pk2(b0.z,b0.w), pk2(b1.x,b1.y), pk2(b1.z,b1.w));
            *(uint4*)(Bp + bi + 4) = make_uint4(pk2(b2.x,b2.y), pk2(b2.z,b2.w), pk2(b3.x,b3.y), pk2(b3.z,b3.w));
        }
        __syncthreads();
        s16x8 af0 = *(const s16x8*)(As + (wv * 32 + l15) * 40 + quad * 8);
        s16x8 af1 = *(const s16x8*)(As + (wv * 32 + 16 + l15) * 40 + quad * 8);
        s16x8 bgf = *(const s16x8*)(Bg + l15 * 40 + quad * 8);
        s16x8 buf = *(const s16x8*)(Bu + l15 * 40 + quad * 8);
        ag0 = MFMA16(af0, bgf, ag0);
        ag1 = MFMA16(af1, bgf, ag1);
        au0 = MFMA16(af0, buf, au0);
        au1 = MFMA16(af1, buf, au1);
        __syncthreads();
    }
    #pragma unroll
    for (int r = 0; r < 4; r++) {
        int row0 = wv * 32 + quad * 4 + r;
        int row1 = row0 + 16;
        float g0 = ag0[r], g1 = ag1[r];
        float u0 = au0[r], u1 = au1[r];
        float v0 = g0 / (1.f + __expf(-g0)) * u0;
        float v1 = g1 / (1.f + __expf(-g1)) * u1;
        C[(size_t)row0 * FF + n0 + l15] = v0;
        C[(size_t)row1 * FF + n0 + l15] = v1;
    }
}

// ---------------- RoPE (unchanged) ----------------
__global__ __launch_bounds__(256) void rope_kernel(float* __restrict__ q,
                                                   float* __restrict__ k,
                                                   const int* __restrict__ offp) {
    int t = blockIdx.x * 256 + threadIdx.x;
    int off = offp[0];
    float* ptr; int dh; int l;
    if (t < 131072) {
        int token = t >> 10;
        int rem = t & 1023;
        int hh = rem >> 6;
        dh = rem & 63;
        ptr = q + token * EE + hh * 128;
        l = token & 15;
    } else {
        int t2 = t - 131072;
        int token = t2 >> 7;
        int rem = t2 & 127;
        int hh = rem >> 6;
        dh = rem & 63;
        ptr = k + token * 256 + hh * 128;
        l = token & 15;
    }
    float pos = (float)(off + l);
    float inv = exp2f(-(float)dh * (13.287712379549449f / 64.0f));
    float ang = pos * inv;
    float s, c;
    sincosf(ang, &s, &c);
    float x0 = ptr[dh], x1 = ptr[dh + 64];
    ptr[dh]      = x0 * c - x1 * s;
    ptr[dh + 64] = x1 * c + x0 * s;
}

// ---------------- Flash-decode MFMA attention ----------------
// Block = (split, b*2+kv). 128 Q-rows (8 heads x 16 tokens) in register A-frags.
// Per 32-key chunk: QK^T (16 mfma/wave) -> online softmax (shfl) -> P bf16 -> PV (16 mfma/wave).
// Writes unnormalized O partial (bf16) + m,l per row.
__global__ __launch_bounds__(256) void attn_kernel(const float* __restrict__ q,
                                                   const float* __restrict__ kn,
                                                   const float* __restrict__ vn,
                                                   const float* __restrict__ ck,
                                                   const float* __restrict__ cv,
                                                   const int* __restrict__ offp,
                                                   unsigned short* __restrict__ Os,
                                                   float* __restrict__ Mw,
                                                   float* __restrict__ Lw) {
    __shared__ __align__(16) char smem[35840];
    short* Qs = (short*)smem;              // 128 rows, stride 136 bf16 (reused below)
    short* Ks = (short*)smem;              // 32 rows, stride 136
    short* Vt = (short*)(smem + 8704);     // 128 d-rows x 32 cols, stride 40
    short* Ps = (short*)(smem + 18944);    // 128 rows x 32 cols, stride 40
    float* mrow = (float*)(smem + 34816);
    float* lrow = (float*)(smem + 35328);

    int t = threadIdx.x;
    int wv = t >> 6, lane = t & 63, quad = lane >> 4, l15 = lane & 15;
    int split = blockIdx.x;
    int bkv = blockIdx.y;
    int b = bkv >> 1, kv = bkv & 1;
    int off = offp[0];
    const float scl = 0.08838834764831845f;

    // stage Q (scaled) to LDS bf16
    {
        int row = t >> 1, half = t & 1;
        int l = row & 15, hg = row >> 4;
        const float* qp = q + (size_t)(b * 16 + l) * EE + (kv * 8 + hg) * 128 + half * 64;
        unsigned* Qu = (unsigned*)(Qs + row * 136 + half * 64);
        #pragma unroll
        for (int i = 0; i < 8; i++) {
            float4 v4 = *(const float4*)(qp + i * 8);
            float4 v5 = *(const float4*)(qp + i * 8 + 4);
            *(uint4*)(Qu + i * 4) = make_uint4(pk2(v4.x*scl, v4.y*scl), pk2(v4.z*scl, v4.w*scl),
                                               pk2(v5.x*scl, v5.y*scl), pk2(v5.z*scl, v5.w*scl));
        }
    }
    if (t < 128) { mrow[t] = -1e30f; lrow[t] = 0.f; }
    __syncthreads();

    // Q A-frags into registers: wave wv owns rows [wv*32, wv*32+32)
    s16x8 qf[2][4];
    #pragma unroll
    for (int mt = 0; mt < 2; mt++)
        #pragma unroll
        for (int ks = 0; ks < 4; ks++)
            qf[mt][ks] = *(const s16x8*)(Qs + (wv * 32 + mt * 16 + l15) * 136 + ks * 32 + quad * 8);

    f32x4 oacc[2][8];
    #pragma unroll
    for (int mt = 0; mt < 2; mt++)
        #pragma unroll
        for (int nt = 0; nt < 8; nt++)
            oacc[mt][nt] = (f32x4){0.f, 0.f, 0.f, 0.f};

    int s_begin = split * 128;
    int s_end = (split == NSPLIT - 1) ? STOT : s_begin + 128;

    for (int s0 = s_begin; s0 < s_end; s0 += 32) {
        int cs = min(32, s_end - s0);
        __syncthreads();   // prior-iter LDS reads done
        // stage K chunk (bf16)
        {
            int key = t >> 3, dc = t & 7;
            int s = s0 + key; if (s > STOT - 1) s = STOT - 1;
            const float* kp = (s < S0C)
                ? ck + ((size_t)(b * 2 + kv) * S0C + s) * 128 + dc * 16
                : kn + (size_t)(b * 16 + (s - S0C)) * 256 + kv * 128 + dc * 16;
            float4 k0v = *(const float4*)(kp);
            float4 k1v = *(const float4*)(kp + 4);
            float4 k2v = *(const float4*)(kp + 8);
            float4 k3v = *(const float4*)(kp + 12);
            unsigned* Ku = (unsigned*)(Ks + key * 136 + dc * 16);
            *(uint4*)(Ku)     = make_uint4(pk2(k0v.x,k0v.y), pk2(k0v.z,k0v.w), pk2(k1v.x,k1v.y), pk2(k1v.z,k1v.w));
            *(uint4*)(Ku + 4) = make_uint4(pk2(k2v.x,k2v.y), pk2(k2v.z,k2v.w), pk2(k3v.x,k3v.y), pk2(k3v.z,k3v.w));
        }
        // stage V transposed (bf16): Vt[d][c]
        {
            int c = t & 31, dch = t >> 5;
            int s = s0 + c; if (s > STOT - 1) s = STOT - 1;
            const float* vp = (s < S0C)
                ? cv + ((size_t)(b * 2 + kv) * S0C + s) * 128 + dch * 16
                : vn + (size_t)(b * 16 + (s - S0C)) * 256 + kv * 128 + dch * 16;
            float vv[16];
            *(float4*)(vv)      = *(const float4*)(vp);
            *(float4*)(vv + 4)  = *(const float4*)(vp + 4);
            *(float4*)(vv + 8)  = *(const float4*)(vp + 8);
            *(float4*)(vv + 12) = *(const float4*)(vp + 12);
            #pragma unroll
            for (int j = 0; j < 16; j++)
                Vt[(dch * 16 + j) * 40 + c] = (short)f2bfu(vv[j]);
        }
        __syncthreads();
        // QK^T
        f32x4 sa[2][2];
        sa[0][0] = (f32x4){0.f,0.f,0.f,0.f}; sa[0][1] = sa[0][0];
        sa[1][0] = sa[0][0];                 sa[1][1] = sa[0][0];
        #pragma unroll
        for (int ks = 0; ks < 4; ks++) {
            #pragma unroll
            for (int nt = 0; nt < 2; nt++) {
                s16x8 kf = *(const s16x8*)(Ks + (nt * 16 + l15) * 136 + ks * 32 + quad * 8);
                sa[0][nt] = MFMA16(qf[0][ks], kf, sa[0][nt]);
                sa[1][nt] = MFMA16(qf[1][ks], kf, sa[1][nt]);
            }
        }
        // online softmax; C-layout: row = base + quad*4 + r, col = s0 + nt*16 + l15
        float alpha[2][4];
        #pragma unroll
        for (int mt = 0; mt < 2; mt++) {
            #pragma unroll
            for (int r = 0; r < 4; r++) {
                int row = wv * 32 + mt * 16 + quad * 4 + r;
                int ltok = row & 15;
                float s0v = sa[mt][0][r];
                float s1v = sa[mt][1][r];
                int g0 = s0 + l15, g1 = s0 + 16 + l15;
                bool ok0 = (l15 < cs) && (g0 <= off + ltok);
                bool ok1 = (16 + l15 < cs) && (g1 <= off + ltok);
                s0v = ok0 ? s0v : -3e38f;
                s1v = ok1 ? s1v : -3e38f;
                float mc = fmaxf(s0v, s1v);
                mc = fmaxf(mc, __shfl_xor(mc, 1));
                mc = fmaxf(mc, __shfl_xor(mc, 2));
                mc = fmaxf(mc, __shfl_xor(mc, 4));
                mc = fmaxf(mc, __shfl_xor(mc, 8));
                float mold = mrow[row];
                float mnew = fmaxf(mold, mc);
                float al = __expf(mold - mnew);
                float p0 = __expf(s0v - mnew);
                float p1 = __expf(s1v - mnew);
                float rs = p0 + p1;
                rs += __shfl_xor(rs, 1);
                rs += __shfl_xor(rs, 2);
                rs += __shfl_xor(rs, 4);
                rs += __shfl_xor(rs, 8);
                if (l15 == 0) { mrow[row] = mnew; lrow[row] = lrow[row] * al + rs; }
                alpha[mt][r] = al;
                Ps[row * 40 + l15] = (short)f2bfu(p0);
                Ps[row * 40 + 16 + l15] = (short)f2bfu(p1);
            }
        }
        // rescale O accumulators
        #pragma unroll
        for (int mt = 0; mt < 2; mt++)
            #pragma unroll
            for (int nt = 0; nt < 8; nt++)
                #pragma unroll
                for (int r = 0; r < 4; r++)
                    oacc[mt][nt][r] *= alpha[mt][r];
        // PV (same-wave P rows; no barrier needed)
        s16x8 pf0 = *(const s16x8*)(Ps + (wv * 32 + l15) * 40 + quad * 8);
        s16x8 pf1 = *(const s16x8*)(Ps + (wv * 32 + 16 + l15) * 40 + quad * 8);
        #pragma unroll
        for (int nt = 0; nt < 8; nt++) {
            s16x8 vf = *(const s16x8*)(Vt + (nt * 16 + l15) * 40 + quad * 8);
            oacc[0][nt] = MFMA16(pf0, vf, oacc[0][nt]);
            oacc[1][nt] = MFMA16(pf1, vf, oacc[1][nt]);
        }
    }

    __syncthreads();
    size_t obase = (size_t)(split * 16 + bkv) * 128;
    #pragma unroll
    for (int mt = 0; mt < 2; mt++)
        #pragma unroll
        for (int nt = 0; nt < 8; nt++)
            #pragma unroll
            for (int r = 0; r < 4; r++) {
                int row = wv * 32 + mt * 16 + quad * 4 + r;
                int d = nt * 16 + l15;
                Os[(obase + row) * 128 + d] = f2bfu(oacc[mt][nt][r]);
            }
    if (t < 128) { Mw[obase + t] = mrow[t]; Lw[obase + t] = lrow[t]; }
}

// ---------------- merge split partials -> ob ----------------
__global__ __launch_bounds__(256) void merge_kernel(const unsigned short* __restrict__ Os,
                                                    const float* __restrict__ Mw,
                                                    const float* __restrict__ Lw,
                                                    float* __restrict__ ob) {
    int blk = blockIdx.x;          // 128 blocks
    int bkv = blk >> 3, rg = blk & 7;
    int b = bkv >> 1, kv = bkv & 1;
    int t = threadIdx.x;
    int rowl = t >> 4;             // 0..15
    int row = rg * 16 + rowl;
    int dchunk = (t & 15) * 8;
    float M = -3e38f;
    for (int s = 0; s < NSPLIT; s++)
        M = fmaxf(M, Mw[((size_t)s * 16 + bkv) * 128 + row]);
    float denom = 0.f;
    float o[8];
    #pragma unroll
    for (int j = 0; j < 8; j++) o[j] = 0.f;
    for (int s = 0; s < NSPLIT; s++) {
        size_t base = ((size_t)s * 16 + bkv) * 128 + row;
        float w = __expf(Mw[base] - M);
        denom += Lw[base] * w;
        uint4 u = *(const uint4*)(Os + base * 128 + dchunk);
        o[0] += w * bf2f((unsigned short)(u.x & 0xffff));
        o[1] += w * bf2f((unsigned short)(u.x >> 16));
        o[2] += w * bf2f((unsigned short)(u.y & 0xffff));
        o[3] += w * bf2f((unsigned short)(u.y >> 16));
        o[4] += w * bf2f((unsigned short)(u.z & 0xffff));
        o[5] += w * bf2f((unsigned short)(u.z >> 16));
        o[6] += w * bf2f((unsigned short)(u.w & 0xffff));
        o[7] += w * bf2f((unsigned short)(u.w >> 16));
    }
    float inv = 1.f / denom;
    float* dst = ob + (size_t)(b * 16 + rowl) * EE + (kv * 8 + rg) * 128 + dchunk;
    #pragma unroll
    for (int j = 0; j < 8; j++) dst[j] = o[j] * inv;
}

// ---------------- launch ----------------
extern "C" void kernel_launch(void* const* d_in, const int* in_sizes, int n_in,
                              void* d_out, int out_size, void* d_ws, size_t ws_size,
                              hipStream_t stream) {
    const float* x        = (const float*)d_in[0];
    const float* cache_k  = (const float*)d_in[1];
    const float* cache_v  = (const float*)d_in[2];
    const float* wq       = (const float*)d_in[3];
    const float* wk       = (const float*)d_in[4];
    const float* wv       = (const float*)d_in[5];
    const float* wo       = (const float*)d_in[6];
    const float* bq       = (const float*)d_in[7];
    const float* bk       = (const float*)d_in[8];
    const float* bv       = (const float*)d_in[9];
    const float* w_gate   = (const float*)d_in[10];
    const float* w_up     = (const float*)d_in[11];
    const float* w_down   = (const float*)d_in[12];
    const float* w_in_ln  = (const float*)d_in[13];
    const float* w_post_ln= (const float*)d_in[14];
    const int*   offp     = (const int*)d_in[15];
    float* out = (float*)d_out;

    float* ws = (float*)d_ws;
    // persistent: xn (reused as hn), hb
    float* xn = ws;                          // 262144
    float* hb = ws + 262144;                 // 262144
    // transient block (base T = 524288 floats)
    const size_t T = 524288;
    float* qb = ws + T;                      // 262144
    float* kb = ws + T + 262144;             // 32768
    float* vb = ws + T + 294912;             // 32768
    float* ob = ws + T + 327680;             // 262144
    unsigned short* Osw = (unsigned short*)(ws + T + 589824);   // 8.39M bf16 = 4194304 floats
    float* Mw = ws + T + 4784128;            // 65536
    float* Lw = ws + T + 4849664;            // 65536  (end: 5439488 floats = 21.8 MB)
    float* gb = ws + T;                      // 720896 (reuses qb..Os region, dead by then)

    rmsnorm_kernel<<<MM, 256, 0, stream>>>(x, w_in_ln, xn);
    qkv_kernel<<<160, 256, 0, stream>>>(xn, wq, wk, wv, bq, bk, bv, qb, kb, vb);
    rope_kernel<<<576, 256, 0, stream>>>(qb, kb, offp);
    attn_kernel<<<dim3(NSPLIT, 16), 256, 0, stream>>>(qb, kb, vb, cache_k, cache_v, offp, Osw, Mw, Lw);
    merge_kernel<<<128, 256, 0, stream>>>(Osw, Mw, Lw, ob);
    gemm16_kernel<<<128, 256, 0, stream>>>(ob, wo, nullptr, x, hb, 2048, 2048);
    rmsnorm_kernel<<<MM, 256, 0, stream>>>(hb, w_post_ln, xn);
    gateup_kernel<<<352, 256, 0, stream>>>(xn, w_gate, w_up, gb);
    gemm16_kernel<<<128, 256, 0, stream>>>(gb, w_down, nullptr, hb, out, 5632, 2048);
}

// Round 3
// 349.820 us; speedup vs baseline: 4.8870x; 1.9402x over previous
//
#include <hip/hip_runtime.h>
#include <math.h>

// Qwen2 block: B=8 L=16 E=2048 S0=4096 F=5632 H=16 HKV=2 D=128
#define MM 128
#define EE 2048
#define FF 5632
#define S0C 4096
#define STOT 4112
#define NSPLIT 32
#define LDQKV 2560

typedef float f32x4 __attribute__((ext_vector_type(4)));
typedef short s16x8 __attribute__((ext_vector_type(8)));

#define MFMA16(a, b, c) __builtin_amdgcn_mfma_f32_16x16x32_bf16(a, b, c, 0, 0, 0)

__device__ __forceinline__ unsigned short f2bfu(float f) {
    unsigned u = __float_as_uint(f);
    u += 0x7fffu + ((u >> 16) & 1u);
    return (unsigned short)(u >> 16);
}
__device__ __forceinline__ unsigned pk2(float lo, float hi) {
    return (unsigned)f2bfu(lo) | ((unsigned)f2bfu(hi) << 16);
}
__device__ __forceinline__ float bf2f(unsigned short u) {
    return __uint_as_float(((unsigned)u) << 16);
}

// ---------------- RMSNorm ----------------
__global__ __launch_bounds__(256) void rmsnorm_kernel(const float* __restrict__ x,
                                                      const float* __restrict__ w,
                                                      float* __restrict__ out) {
    int row = blockIdx.x;
    int t = threadIdx.x;
    const float4* xr = (const float4*)(x + row * EE);
    float4 a = xr[t];
    float4 b = xr[t + 256];
    float ss = a.x*a.x + a.y*a.y + a.z*a.z + a.w*a.w
             + b.x*b.x + b.y*b.y + b.z*b.z + b.w*b.w;
    #pragma unroll
    for (int o = 32; o > 0; o >>= 1) ss += __shfl_down(ss, o);
    __shared__ float red[4];
    if ((t & 63) == 0) red[t >> 6] = ss;
    __syncthreads();
    float tot = red[0] + red[1] + red[2] + red[3];
    float inv = rsqrtf(tot * (1.0f / (float)EE) + 1e-6f);
    const float4* wr = (const float4*)w;
    float4 w0 = wr[t], w1 = wr[t + 256];
    float4 o0, o1;
    o0.x = a.x*inv*w0.x; o0.y = a.y*inv*w0.y; o0.z = a.z*inv*w0.z; o0.w = a.w*inv*w0.w;
    o1.x = b.x*inv*w1.x; o1.y = b.y*inv*w1.y; o1.z = b.z*inv*w1.z; o1.w = b.w*inv*w1.w;
    float4* orow = (float4*)(out + row * EE);
    orow[t] = o0;
    orow[t + 256] = o1;
}

// ---------------- split-K bf16 MFMA GEMM ----------------
// C-tile 128x64 per block, K-chunk Kc per grid-y slice. P[sk][128][N] fp32 partials.
// W rows selected from up to 3 matrices (col segments at cut1/cut2), each [*, K] row-major.
__global__ __launch_bounds__(256) void gemm_splitk(const float* __restrict__ A,
                                                   const float* __restrict__ W0,
                                                   const float* __restrict__ W1,
                                                   const float* __restrict__ W2,
                                                   int cut1, int cut2,
                                                   int K, int Kc,
                                                   float* __restrict__ P, int N) {
    __shared__ __align__(16) short As[128 * 32];  // frag-ordered, 64B row stride
    __shared__ __align__(16) short Bs[64 * 32];
    int t = threadIdx.x;
    int wv = t >> 6, lane = t & 63, quad = lane >> 4, l15 = lane & 15;
    int n0 = blockIdx.x * 64;
    int k0 = blockIdx.y * Kc;
    const float* Wb; int nl;
    if (n0 < cut1)      { Wb = W0; nl = n0; }
    else if (n0 < cut2) { Wb = W1; nl = n0 - cut1; }
    else                { Wb = W2; nl = n0 - cut2; }
    int rq = t >> 2;            // 0..63
    int kq = (t & 3) * 8;       // 0,8,16,24
    const float* Ar0 = A + (size_t)rq * K + k0 + kq;
    const float* Ar1 = Ar0 + (size_t)64 * K;
    const float* Br  = Wb + (size_t)(nl + rq) * K + k0 + kq;
    int nk = Kc >> 5;
    f32x4 acc[4][2];
    #pragma unroll
    for (int mi = 0; mi < 4; mi++)
        #pragma unroll
        for (int ni = 0; ni < 2; ni++)
            acc[mi][ni] = (f32x4){0.f, 0.f, 0.f, 0.f};
    int mh = (wv & 1) * 64, nh = (wv >> 1) * 32;

    float4 a0 = *(const float4*)(Ar0);
    float4 a1 = *(const float4*)(Ar0 + 4);
    float4 a2 = *(const float4*)(Ar1);
    float4 a3 = *(const float4*)(Ar1 + 4);
    float4 b0 = *(const float4*)(Br);
    float4 b1 = *(const float4*)(Br + 4);

    for (int ks = 0; ks < nk; ks++) {
        __syncthreads();
        *(uint4*)(As + rq * 32 + kq) =
            make_uint4(pk2(a0.x,a0.y), pk2(a0.z,a0.w), pk2(a1.x,a1.y), pk2(a1.z,a1.w));
        *(uint4*)(As + (rq + 64) * 32 + kq) =
            make_uint4(pk2(a2.x,a2.y), pk2(a2.z,a2.w), pk2(a3.x,a3.y), pk2(a3.z,a3.w));
        *(uint4*)(Bs + rq * 32 + kq) =
            make_uint4(pk2(b0.x,b0.y), pk2(b0.z,b0.w), pk2(b1.x,b1.y), pk2(b1.z,b1.w));
        if (ks + 1 < nk) {
            const float* p0 = Ar0 + (ks + 1) * 32;
            const float* p1 = Ar1 + (ks + 1) * 32;
            const float* pb = Br  + (ks + 1) * 32;
            a0 = *(const float4*)(p0); a1 = *(const float4*)(p0 + 4);
            a2 = *(const float4*)(p1); a3 = *(const float4*)(p1 + 4);
            b0 = *(const float4*)(pb); b1 = *(const float4*)(pb + 4);
        }
        __syncthreads();
        s16x8 af0 = *(const s16x8*)(As + (mh +  0 + l15) * 32 + quad * 8);
        s16x8 af1 = *(const s16x8*)(As + (mh + 16 + l15) * 32 + quad * 8);
        s16x8 af2 = *(const s16x8*)(As + (mh + 32 + l15) * 32 + quad * 8);
        s16x8 af3 = *(const s16x8*)(As + (mh + 48 + l15) * 32 + quad * 8);
        s16x8 bf0 = *(const s16x8*)(Bs + (nh +  0 + l15) * 32 + quad * 8);
        s16x8 bf1 = *(const s16x8*)(Bs + (nh + 16 + l15) * 32 + quad * 8);
        acc[0][0] = MFMA16(af0, bf0, acc[0][0]);
        acc[1][0] = MFMA16(af1, bf0, acc[1][0]);
        acc[2][0] = MFMA16(af2, bf0, acc[2][0]);
        acc[3][0] = MFMA16(af3, bf0, acc[3][0]);
        acc[0][1] = MFMA16(af0, bf1, acc[0][1]);
        acc[1][1] = MFMA16(af1, bf1, acc[1][1]);
        acc[2][1] = MFMA16(af2, bf1, acc[2][1]);
        acc[3][1] = MFMA16(af3, bf1, acc[3][1]);
    }
    size_t pb = (size_t)blockIdx.y * MM * N + n0;
    #pragma unroll
    for (int mi = 0; mi < 4; mi++)
        #pragma unroll
        for (int ni = 0; ni < 2; ni++)
            #pragma unroll
            for (int r = 0; r < 4; r++)
                P[pb + (size_t)(mh + mi * 16 + quad * 4 + r) * N + nh + ni * 16 + l15]
                    = acc[mi][ni][r];
}

// ---------------- reduce kernels ----------------
__global__ __launch_bounds__(256) void reduce_qkv(const float* __restrict__ P,
                                                  const float* __restrict__ bq,
                                                  const float* __restrict__ bk,
                                                  const float* __restrict__ bv,
                                                  float* __restrict__ C) {
    int e4 = (blockIdx.x * 256 + threadIdx.x) * 4;   // over 128*2560
    f32x4 s = {0.f, 0.f, 0.f, 0.f};
    #pragma unroll
    for (int sx = 0; sx < 8; sx++)
        s += *(const f32x4*)(P + (size_t)sx * (MM * LDQKV) + e4);
    int c = e4 % LDQKV;
    const float* bptr; int cl;
    if (c < 2048)      { bptr = bq; cl = c; }
    else if (c < 2304) { bptr = bk; cl = c - 2048; }
    else               { bptr = bv; cl = c - 2304; }
    s += *(const f32x4*)(bptr + cl);
    *(f32x4*)(C + e4) = s;
}

__global__ __launch_bounds__(256) void reduce_res(const float* __restrict__ P,
                                                  const float* __restrict__ res,
                                                  float* __restrict__ C) {
    int e4 = (blockIdx.x * 256 + threadIdx.x) * 4;   // over 128*2048
    f32x4 s = *(const f32x4*)(res + e4);
    #pragma unroll
    for (int sx = 0; sx < 8; sx++)
        s += *(const f32x4*)(P + (size_t)sx * (MM * EE) + e4);
    *(f32x4*)(C + e4) = s;
}

__global__ __launch_bounds__(256) void reduce_gateup(const float* __restrict__ P,
                                                     float* __restrict__ gb) {
    int e4 = (blockIdx.x * 256 + threadIdx.x) * 4;   // over 128*5632
    int m = e4 / FF, f = e4 % FF;
    f32x4 g = {0.f,0.f,0.f,0.f}, u = g;
    #pragma unroll
    for (int sx = 0; sx < 2; sx++) {
        size_t base = (size_t)sx * (MM * 11264) + (size_t)m * 11264;
        g += *(const f32x4*)(P + base + f);
        u += *(const f32x4*)(P + base + 5632 + f);
    }
    f32x4 r;
    #pragma unroll
    for (int j = 0; j < 4; j++)
        r[j] = g[j] / (1.f + __expf(-g[j])) * u[j];
    *(f32x4*)(gb + e4) = r;
}

// ---------------- RoPE (qkv packed buffer, ld=2560) ----------------
__global__ __launch_bounds__(256) void rope_kernel(float* __restrict__ qkv,
                                                   const int* __restrict__ offp) {
    int t = blockIdx.x * 256 + threadIdx.x;
    int off = offp[0];
    float* ptr; int dh; int l;
    if (t < 131072) {                   // q: 128 tok * 16 heads * 64
        int token = t >> 10;
        int rem = t & 1023;
        int hh = rem >> 6;
        dh = rem & 63;
        ptr = qkv + token * LDQKV + hh * 128;
        l = token & 15;
    } else {                            // k: 128 tok * 2 kvheads * 64
        int t2 = t - 131072;
        int token = t2 >> 7;
        int rem = t2 & 127;
        int hh = rem >> 6;
        dh = rem & 63;
        ptr = qkv + 2048 + token * LDQKV + hh * 128;
        l = token & 15;
    }
    float pos = (float)(off + l);
    float inv = exp2f(-(float)dh * (13.287712379549449f / 64.0f));
    float ang = pos * inv;
    float s, c;
    sincosf(ang, &s, &c);
    float x0 = ptr[dh], x1 = ptr[dh + 64];
    ptr[dh]      = x0 * c - x1 * s;
    ptr[dh + 64] = x1 * c + x0 * s;
}

// ---------------- Flash-decode MFMA attention ----------------
__global__ __launch_bounds__(256) void attn_kernel(const float* __restrict__ qkv,
                                                   const float* __restrict__ ck,
                                                   const float* __restrict__ cv,
                                                   const int* __restrict__ offp,
                                                   unsigned short* __restrict__ Os,
                                                   float* __restrict__ Mw,
                                                   float* __restrict__ Lw) {
    __shared__ __align__(16) char smem[35840];
    short* Qs = (short*)smem;              // 128 rows, stride 136
    short* Ks = (short*)smem;              // 32 rows, stride 136
    short* Vt = (short*)(smem + 8704);     // 128 d-rows x 32, stride 40
    short* Ps = (short*)(smem + 18944);    // 128 rows x 32, stride 40
    float* mrow = (float*)(smem + 34816);
    float* lrow = (float*)(smem + 35328);

    int t = threadIdx.x;
    int wv = t >> 6, lane = t & 63, quad = lane >> 4, l15 = lane & 15;
    int split = blockIdx.x;
    int bkv = blockIdx.y;
    int b = bkv >> 1, kv = bkv & 1;
    int off = offp[0];
    const float scl = 0.08838834764831845f;

    {
        int row = t >> 1, half = t & 1;
        int l = row & 15, hg = row >> 4;
        const float* qp = qkv + (size_t)(b * 16 + l) * LDQKV + (kv * 8 + hg) * 128 + half * 64;
        unsigned* Qu = (unsigned*)(Qs + row * 136 + half * 64);
        #pragma unroll
        for (int i = 0; i < 8; i++) {
            float4 v4 = *(const float4*)(qp + i * 8);
            float4 v5 = *(const float4*)(qp + i * 8 + 4);
            *(uint4*)(Qu + i * 4) = make_uint4(pk2(v4.x*scl, v4.y*scl), pk2(v4.z*scl, v4.w*scl),
                                               pk2(v5.x*scl, v5.y*scl), pk2(v5.z*scl, v5.w*scl));
        }
    }
    if (t < 128) { mrow[t] = -1e30f; lrow[t] = 0.f; }
    __syncthreads();

    s16x8 qf[2][4];
    #pragma unroll
    for (int mt = 0; mt < 2; mt++)
        #pragma unroll
        for (int ks = 0; ks < 4; ks++)
            qf[mt][ks] = *(const s16x8*)(Qs + (wv * 32 + mt * 16 + l15) * 136 + ks * 32 + quad * 8);

    f32x4 oacc[2][8];
    #pragma unroll
    for (int mt = 0; mt < 2; mt++)
        #pragma unroll
        for (int nt = 0; nt < 8; nt++)
            oacc[mt][nt] = (f32x4){0.f, 0.f, 0.f, 0.f};

    int s_begin = split * 128;
    int s_end = (split == NSPLIT - 1) ? STOT : s_begin + 128;

    for (int s0 = s_begin; s0 < s_end; s0 += 32) {
        int cs = min(32, s_end - s0);
        __syncthreads();
        {
            int key = t >> 3, dc = t & 7;
            int s = s0 + key; if (s > STOT - 1) s = STOT - 1;
            const float* kp = (s < S0C)
                ? ck + ((size_t)(b * 2 + kv) * S0C + s) * 128 + dc * 16
                : qkv + 2048 + (size_t)(b * 16 + (s - S0C)) * LDQKV + kv * 128 + dc * 16;
            float4 k0v = *(const float4*)(kp);
            float4 k1v = *(const float4*)(kp + 4);
            float4 k2v = *(const float4*)(kp + 8);
            float4 k3v = *(const float4*)(kp + 12);
            unsigned* Ku = (unsigned*)(Ks + key * 136 + dc * 16);
            *(uint4*)(Ku)     = make_uint4(pk2(k0v.x,k0v.y), pk2(k0v.z,k0v.w), pk2(k1v.x,k1v.y), pk2(k1v.z,k1v.w));
            *(uint4*)(Ku + 4) = make_uint4(pk2(k2v.x,k2v.y), pk2(k2v.z,k2v.w), pk2(k3v.x,k3v.y), pk2(k3v.z,k3v.w));
        }
        {
            int c = t & 31, dch = t >> 5;
            int s = s0 + c; if (s > STOT - 1) s = STOT - 1;
            const float* vp = (s < S0C)
                ? cv + ((size_t)(b * 2 + kv) * S0C + s) * 128 + dch * 16
                : qkv + 2304 + (size_t)(b * 16 + (s - S0C)) * LDQKV + kv * 128 + dch * 16;
            float vv[16];
            *(float4*)(vv)      = *(const float4*)(vp);
            *(float4*)(vv + 4)  = *(const float4*)(vp + 4);
            *(float4*)(vv + 8)  = *(const float4*)(vp + 8);
            *(float4*)(vv + 12) = *(const float4*)(vp + 12);
            #pragma unroll
            for (int j = 0; j < 16; j++)
                Vt[(dch * 16 + j) * 40 + c] = (short)f2bfu(vv[j]);
        }
        __syncthreads();
        f32x4 sa[2][2];
        sa[0][0] = (f32x4){0.f,0.f,0.f,0.f}; sa[0][1] = sa[0][0];
        sa[1][0] = sa[0][0];                 sa[1][1] = sa[0][0];
        #pragma unroll
        for (int ks = 0; ks < 4; ks++) {
            #pragma unroll
            for (int nt = 0; nt < 2; nt++) {
                s16x8 kf = *(const s16x8*)(Ks + (nt * 16 + l15) * 136 + ks * 32 + quad * 8);
                sa[0][nt] = MFMA16(qf[0][ks], kf, sa[0][nt]);
                sa[1][nt] = MFMA16(qf[1][ks], kf, sa[1][nt]);
            }
        }
        float alpha[2][4];
        #pragma unroll
        for (int mt = 0; mt < 2; mt++) {
            #pragma unroll
            for (int r = 0; r < 4; r++) {
                int row = wv * 32 + mt * 16 + quad * 4 + r;
                int ltok = row & 15;
                float s0v = sa[mt][0][r];
                float s1v = sa[mt][1][r];
                int g0 = s0 + l15, g1 = s0 + 16 + l15;
                bool ok0 = (l15 < cs) && (g0 <= off + ltok);
                bool ok1 = (16 + l15 < cs) && (g1 <= off + ltok);
                s0v = ok0 ? s0v : -3e38f;
                s1v = ok1 ? s1v : -3e38f;
                float mc = fmaxf(s0v, s1v);
                mc = fmaxf(mc, __shfl_xor(mc, 1));
                mc = fmaxf(mc, __shfl_xor(mc, 2));
                mc = fmaxf(mc, __shfl_xor(mc, 4));
                mc = fmaxf(mc, __shfl_xor(mc, 8));
                float mold = mrow[row];
                float mnew = fmaxf(mold, mc);
                float al = __expf(mold - mnew);
                float p0 = __expf(s0v - mnew);
                float p1 = __expf(s1v - mnew);
                float rs = p0 + p1;
                rs += __shfl_xor(rs, 1);
                rs += __shfl_xor(rs, 2);
                rs += __shfl_xor(rs, 4);
                rs += __shfl_xor(rs, 8);
                if (l15 == 0) { mrow[row] = mnew; lrow[row] = lrow[row] * al + rs; }
                alpha[mt][r] = al;
                Ps[row * 40 + l15] = (short)f2bfu(p0);
                Ps[row * 40 + 16 + l15] = (short)f2bfu(p1);
            }
        }
        #pragma unroll
        for (int mt = 0; mt < 2; mt++)
            #pragma unroll
            for (int nt = 0; nt < 8; nt++)
                #pragma unroll
                for (int r = 0; r < 4; r++)
                    oacc[mt][nt][r] *= alpha[mt][r];
        s16x8 pf0 = *(const s16x8*)(Ps + (wv * 32 + l15) * 40 + quad * 8);
        s16x8 pf1 = *(const s16x8*)(Ps + (wv * 32 + 16 + l15) * 40 + quad * 8);
        #pragma unroll
        for (int nt = 0; nt < 8; nt++) {
            s16x8 vf = *(const s16x8*)(Vt + (nt * 16 + l15) * 40 + quad * 8);
            oacc[0][nt] = MFMA16(pf0, vf, oacc[0][nt]);
            oacc[1][nt] = MFMA16(pf1, vf, oacc[1][nt]);
        }
    }

    __syncthreads();
    size_t obase = (size_t)(split * 16 + bkv) * 128;
    #pragma unroll
    for (int mt = 0; mt < 2; mt++)
        #pragma unroll
        for (int nt = 0; nt < 8; nt++)
            #pragma unroll
            for (int r = 0; r < 4; r++) {
                int row = wv * 32 + mt * 16 + quad * 4 + r;
                int d = nt * 16 + l15;
                Os[(obase + row) * 128 + d] = f2bfu(oacc[mt][nt][r]);
            }
    if (t < 128) { Mw[obase + t] = mrow[t]; Lw[obase + t] = lrow[t]; }
}

// ---------------- merge split partials -> ob ----------------
__global__ __launch_bounds__(256) void merge_kernel(const unsigned short* __restrict__ Os,
                                                    const float* __restrict__ Mw,
                                                    const float* __restrict__ Lw,
                                                    float* __restrict__ ob) {
    int blk = blockIdx.x;
    int bkv = blk >> 3, rg = blk & 7;
    int b = bkv >> 1, kv = bkv & 1;
    int t = threadIdx.x;
    int rowl = t >> 4;
    int row = rg * 16 + rowl;
    int dchunk = (t & 15) * 8;
    float M = -3e38f;
    for (int s = 0; s < NSPLIT; s++)
        M = fmaxf(M, Mw[((size_t)s * 16 + bkv) * 128 + row]);
    float denom = 0.f;
    float o[8];
    #pragma unroll
    for (int j = 0; j < 8; j++) o[j] = 0.f;
    for (int s = 0; s < NSPLIT; s++) {
        size_t base = ((size_t)s * 16 + bkv) * 128 + row;
        float w = __expf(Mw[base] - M);
        denom += Lw[base] * w;
        uint4 u = *(const uint4*)(Os + base * 128 + dchunk);
        o[0] += w * bf2f((unsigned short)(u.x & 0xffff));
        o[1] += w * bf2f((unsigned short)(u.x >> 16));
        o[2] += w * bf2f((unsigned short)(u.y & 0xffff));
        o[3] += w * bf2f((unsigned short)(u.y >> 16));
        o[4] += w * bf2f((unsigned short)(u.z & 0xffff));
        o[5] += w * bf2f((unsigned short)(u.z >> 16));
        o[6] += w * bf2f((unsigned short)(u.w & 0xffff));
        o[7] += w * bf2f((unsigned short)(u.w >> 16));
    }
    float inv = 1.f / denom;
    float* dst = ob + (size_t)(b * 16 + rowl) * EE + (kv * 8 + rg) * 128 + dchunk;
    #pragma unroll
    for (int j = 0; j < 8; j++) dst[j] = o[j] * inv;
}

// ---------------- launch ----------------
extern "C" void kernel_launch(void* const* d_in, const int* in_sizes, int n_in,
                              void* d_out, int out_size, void* d_ws, size_t ws_size,
                              hipStream_t stream) {
    const float* x        = (const float*)d_in[0];
    const float* cache_k  = (const float*)d_in[1];
    const float* cache_v  = (const float*)d_in[2];
    const float* wq       = (const float*)d_in[3];
    const float* wk       = (const float*)d_in[4];
    const float* wv       = (const float*)d_in[5];
    const float* wo       = (const float*)d_in[6];
    const float* bq       = (const float*)d_in[7];
    const float* bk       = (const float*)d_in[8];
    const float* bv       = (const float*)d_in[9];
    const float* w_gate   = (const float*)d_in[10];
    const float* w_up     = (const float*)d_in[11];
    const float* w_down   = (const float*)d_in[12];
    const float* w_in_ln  = (const float*)d_in[13];
    const float* w_post_ln= (const float*)d_in[14];
    const int*   offp     = (const int*)d_in[15];
    float* out = (float*)d_out;

    float* ws = (float*)d_ws;
    float* xn    = ws;                        // 262144 (also hn)
    float* hb    = ws + 262144;               // 262144
    float* qkvb  = ws + 524288;               // 128*2560 = 327680
    float* ob    = ws + 851968;               // 262144
    float* gb    = ws + 1114112;              // 128*5632 = 720896
    float* R     = ws + 1835008;              // shared region: P (<=2883584) / Os+Mw+Lw (4325376)
    float* P     = R;
    unsigned short* Osw = (unsigned short*)R;
    float* Mw    = R + 4194304;
    float* Lw    = R + 4259840;               // end: 6160384 floats = 24.6 MB

    const int BIG = 1 << 30;

    rmsnorm_kernel<<<MM, 256, 0, stream>>>(x, w_in_ln, xn);
    // QKV: N=2560 (q|k|v), K=2048, SK=8 (Kc=256) -> 320 blocks
    gemm_splitk<<<dim3(40, 8), 256, 0, stream>>>(xn, wq, wk, wv, 2048, 2304, 2048, 256, P, LDQKV);
    reduce_qkv<<<320, 256, 0, stream>>>(P, bq, bk, bv, qkvb);
    rope_kernel<<<576, 256, 0, stream>>>(qkvb, offp);
    attn_kernel<<<dim3(NSPLIT, 16), 256, 0, stream>>>(qkvb, cache_k, cache_v, offp, Osw, Mw, Lw);
    merge_kernel<<<128, 256, 0, stream>>>(Osw, Mw, Lw, ob);
    // O-proj: N=2048, K=2048, SK=8 -> 256 blocks
    gemm_splitk<<<dim3(32, 8), 256, 0, stream>>>(ob, wo, wo, wo, BIG, BIG, 2048, 256, P, EE);
    reduce_res<<<256, 256, 0, stream>>>(P, x, hb);
    rmsnorm_kernel<<<MM, 256, 0, stream>>>(hb, w_post_ln, xn);
    // Gate|Up: N=11264, K=2048, SK=2 (Kc=1024) -> 352 blocks
    gemm_splitk<<<dim3(176, 2), 256, 0, stream>>>(xn, w_gate, w_up, w_up, 5632, BIG, 2048, 1024, P, 11264);
    reduce_gateup<<<704, 256, 0, stream>>>(P, gb);
    // Down: N=2048, K=5632, SK=8 (Kc=704) -> 256 blocks
    gemm_splitk<<<dim3(32, 8), 256, 0, stream>>>(gb, w_down, w_down, w_down, BIG, BIG, 5632, 704, P, EE);
    reduce_res<<<256, 256, 0, stream>>>(P, hb, out);
}

// Round 4
// 336.037 us; speedup vs baseline: 5.0874x; 1.0410x over previous
//
#include <hip/hip_runtime.h>
#include <math.h>

// Qwen2 block: B=8 L=16 E=2048 S0=4096 F=5632 H=16 HKV=2 D=128
#define MM 128
#define EE 2048
#define FF 5632
#define S0C 4096
#define STOT 4112
#define NSPLIT 32
#define LDQKV 2560

typedef float f32x4 __attribute__((ext_vector_type(4)));
typedef short s16x8 __attribute__((ext_vector_type(8)));

#define MFMA16(a, b, c) __builtin_amdgcn_mfma_f32_16x16x32_bf16(a, b, c, 0, 0, 0)

// round-half-up fp32->bf16 (1 VALU); pack two via v_perm (3 VALU / 2 elems)
__device__ __forceinline__ unsigned short f2bfu(float f) {
    return (unsigned short)((__float_as_uint(f) + 0x8000u) >> 16);
}
__device__ __forceinline__ unsigned pk2(float lo, float hi) {
    return __builtin_amdgcn_perm(__float_as_uint(hi) + 0x8000u,
                                 __float_as_uint(lo) + 0x8000u, 0x07060302u);
}
__device__ __forceinline__ float bf2f(unsigned short u) {
    return __uint_as_float(((unsigned)u) << 16);
}

// A-fragment layout for gemm_stream: element (row, k) of A[128][K] lives at
//   (k>>5)*4096 + ((k>>3)&3)*1024 + row*8 + (k&7)    (shorts)
// so a wave's A-frag load (lane: quad=k-octet, l15=row%16) is 4x256B contiguous.

// ---------------- RMSNorm -> bf16 fragged A ----------------
__global__ __launch_bounds__(256) void rmsnorm_bf16(const float* __restrict__ x,
                                                    const float* __restrict__ w,
                                                    unsigned short* __restrict__ out) {
    int row = blockIdx.x;
    int t = threadIdx.x;
    const float4* xr = (const float4*)(x + row * EE);
    float4 a = xr[2 * t];
    float4 b = xr[2 * t + 1];
    float ss = a.x*a.x + a.y*a.y + a.z*a.z + a.w*a.w
             + b.x*b.x + b.y*b.y + b.z*b.z + b.w*b.w;
    #pragma unroll
    for (int o = 32; o > 0; o >>= 1) ss += __shfl_down(ss, o);
    __shared__ float red[4];
    if ((t & 63) == 0) red[t >> 6] = ss;
    __syncthreads();
    float tot = red[0] + red[1] + red[2] + red[3];
    float inv = rsqrtf(tot * (1.0f / (float)EE) + 1e-6f);
    const float4* wr = (const float4*)w;
    float4 w0 = wr[2 * t], w1 = wr[2 * t + 1];
    float4 o0, o1;
    o0.x = a.x*inv*w0.x; o0.y = a.y*inv*w0.y; o0.z = a.z*inv*w0.z; o0.w = a.w*inv*w0.w;
    o1.x = b.x*inv*w1.x; o1.y = b.y*inv*w1.y; o1.z = b.z*inv*w1.z; o1.w = b.w*inv*w1.w;
    unsigned short* dst = out + (t >> 2) * 4096 + (t & 3) * 1024 + row * 8;
    *(uint4*)dst = make_uint4(pk2(o0.x, o0.y), pk2(o0.z, o0.w),
                              pk2(o1.x, o1.y), pk2(o1.z, o1.w));
}

// ---------------- barrier-free streaming GEMM ----------------
// wave = 128 rows x (16*NC) cols; A from fragged bf16 (L2-resident), W fp32 streamed.
// P[sk][128][N] fp32 partials.
template<int NC>
__global__ __launch_bounds__(256) void gemm_stream(const unsigned short* __restrict__ Af,
                                                   const float* __restrict__ W0,
                                                   const float* __restrict__ W1,
                                                   const float* __restrict__ W2,
                                                   int cut1, int cut2,
                                                   int K, int Kc,
                                                   float* __restrict__ P, int N) {
    int t = threadIdx.x;
    int wv = t >> 6, lane = t & 63, quad = lane >> 4, l15 = lane & 15;
    int nb_blk = blockIdx.x * (64 * NC) + wv * (16 * NC);
    const float* Wr[NC];
    #pragma unroll
    for (int c = 0; c < NC; c++) {
        int nb = nb_blk + c * 16;
        const float* Wm; int nn;
        if (nb < cut1)      { Wm = W0; nn = nb; }
        else if (nb < cut2) { Wm = W1; nn = nb - cut1; }
        else                { Wm = W2; nn = nb - cut2; }
        Wr[c] = Wm + (size_t)(nn + l15) * K + blockIdx.y * Kc + quad * 8;
    }
    const unsigned short* ap = Af + ((blockIdx.y * Kc) >> 5) * 4096 + quad * 1024 + l15 * 8;
    int nk = Kc >> 5;

    f32x4 acc[8][NC];
    #pragma unroll
    for (int g = 0; g < 8; g++)
        #pragma unroll
        for (int c = 0; c < NC; c++)
            acc[g][c] = (f32x4){0.f, 0.f, 0.f, 0.f};

    s16x8 an[8];
    float4 w0n[NC], w1n[NC];
    #pragma unroll
    for (int g = 0; g < 8; g++) an[g] = *(const s16x8*)(ap + g * 128);
    #pragma unroll
    for (int c = 0; c < NC; c++) {
        w0n[c] = *(const float4*)(Wr[c]);
        w1n[c] = *(const float4*)(Wr[c] + 4);
    }

    for (int ks = 0; ks < nk; ks++) {
        s16x8 a[8];
        #pragma unroll
        for (int g = 0; g < 8; g++) a[g] = an[g];
        float4 w0[NC], w1[NC];
        #pragma unroll
        for (int c = 0; c < NC; c++) { w0[c] = w0n[c]; w1[c] = w1n[c]; }
        if (ks + 1 < nk) {
            ap += 4096;
            #pragma unroll
            for (int g = 0; g < 8; g++) an[g] = *(const s16x8*)(ap + g * 128);
            #pragma unroll
            for (int c = 0; c < NC; c++) {
                Wr[c] += 32;
                w0n[c] = *(const float4*)(Wr[c]);
                w1n[c] = *(const float4*)(Wr[c] + 4);
            }
        }
        #pragma unroll
        for (int c = 0; c < NC; c++) {
            union { unsigned u[4]; s16x8 v; } bu;
            bu.u[0] = pk2(w0[c].x, w0[c].y);
            bu.u[1] = pk2(w0[c].z, w0[c].w);
            bu.u[2] = pk2(w1[c].x, w1[c].y);
            bu.u[3] = pk2(w1[c].z, w1[c].w);
            s16x8 bf = bu.v;
            #pragma unroll
            for (int g = 0; g < 8; g++)
                acc[g][c] = MFMA16(a[g], bf, acc[g][c]);
        }
    }

    size_t pb = (size_t)blockIdx.y * MM * N;
    #pragma unroll
    for (int c = 0; c < NC; c++)
        #pragma unroll
        for (int g = 0; g < 8; g++)
            #pragma unroll
            for (int r = 0; r < 4; r++) {
                int row = g * 16 + quad * 4 + r;
                P[pb + (size_t)row * N + nb_blk + c * 16 + l15] = acc[g][c][r];
            }
}

// ---------------- reduce kernels ----------------
__global__ __launch_bounds__(256) void reduce_qkv(const float* __restrict__ P,
                                                  const float* __restrict__ bq,
                                                  const float* __restrict__ bk,
                                                  const float* __restrict__ bv,
                                                  float* __restrict__ C) {
    int e4 = (blockIdx.x * 256 + threadIdx.x) * 4;   // over 128*2560
    f32x4 s = {0.f, 0.f, 0.f, 0.f};
    #pragma unroll
    for (int sx = 0; sx < 8; sx++)
        s += *(const f32x4*)(P + (size_t)sx * (MM * LDQKV) + e4);
    int c = e4 % LDQKV;
    const float* bptr; int cl;
    if (c < 2048)      { bptr = bq; cl = c; }
    else if (c < 2304) { bptr = bk; cl = c - 2048; }
    else               { bptr = bv; cl = c - 2304; }
    s += *(const f32x4*)(bptr + cl);
    *(f32x4*)(C + e4) = s;
}

__global__ __launch_bounds__(256) void reduce_res(const float* __restrict__ P,
                                                  const float* __restrict__ res,
                                                  float* __restrict__ C) {
    int e4 = (blockIdx.x * 256 + threadIdx.x) * 4;   // over 128*2048
    f32x4 s = *(const f32x4*)(res + e4);
    #pragma unroll
    for (int sx = 0; sx < 8; sx++)
        s += *(const f32x4*)(P + (size_t)sx * (MM * EE) + e4);
    *(f32x4*)(C + e4) = s;
}

// gate|up partials -> silu(g)*u -> bf16 fragged A (for down-proj, K=5632)
__global__ __launch_bounds__(256) void reduce_gateup(const float* __restrict__ P,
                                                     unsigned short* __restrict__ gbf) {
    int e4 = (blockIdx.x * 256 + threadIdx.x) * 4;   // over 128*5632
    int m = e4 / FF, f = e4 % FF;
    f32x4 g = {0.f,0.f,0.f,0.f}, u = g;
    #pragma unroll
    for (int sx = 0; sx < 2; sx++) {
        size_t base = (size_t)sx * (MM * 11264) + (size_t)m * 11264;
        g += *(const f32x4*)(P + base + f);
        u += *(const f32x4*)(P + base + 5632 + f);
    }
    f32x4 r;
    #pragma unroll
    for (int j = 0; j < 4; j++)
        r[j] = g[j] / (1.f + __expf(-g[j])) * u[j];
    unsigned short* dst = gbf + (f >> 5) * 4096 + ((f >> 3) & 3) * 1024 + m * 8 + (f & 7);
    *(uint2*)dst = make_uint2(pk2(r[0], r[1]), pk2(r[2], r[3]));
}

// ---------------- RoPE (qkv packed buffer, ld=2560) ----------------
__global__ __launch_bounds__(256) void rope_kernel(float* __restrict__ qkv,
                                                   const int* __restrict__ offp) {
    int t = blockIdx.x * 256 + threadIdx.x;
    int off = offp[0];
    float* ptr; int dh; int l;
    if (t < 131072) {                   // q: 128 tok * 16 heads * 64
        int token = t >> 10;
        int rem = t & 1023;
        int hh = rem >> 6;
        dh = rem & 63;
        ptr = qkv + token * LDQKV + hh * 128;
        l = token & 15;
    } else {                            // k: 128 tok * 2 kvheads * 64
        int t2 = t - 131072;
        int token = t2 >> 7;
        int rem = t2 & 127;
        int hh = rem >> 6;
        dh = rem & 63;
        ptr = qkv + 2048 + token * LDQKV + hh * 128;
        l = token & 15;
    }
    float pos = (float)(off + l);
    float inv = exp2f(-(float)dh * (13.287712379549449f / 64.0f));
    float ang = pos * inv;
    float s, c;
    sincosf(ang, &s, &c);
    float x0 = ptr[dh], x1 = ptr[dh + 64];
    ptr[dh]      = x0 * c - x1 * s;
    ptr[dh + 64] = x1 * c + x0 * s;
}

// ---------------- Flash-decode MFMA attention ----------------
__global__ __launch_bounds__(256) void attn_kernel(const float* __restrict__ qkv,
                                                   const float* __restrict__ ck,
                                                   const float* __restrict__ cv,
                                                   const int* __restrict__ offp,
                                                   unsigned short* __restrict__ Os,
                                                   float* __restrict__ Mw,
                                                   float* __restrict__ Lw) {
    __shared__ __align__(16) char smem[35840];
    short* Qs = (short*)smem;              // 128 rows, stride 136
    short* Ks = (short*)smem;              // 32 rows, stride 136
    short* Vt = (short*)(smem + 8704);     // 128 d-rows x 32, stride 40
    short* Ps = (short*)(smem + 18944);    // 128 rows x 32, stride 40
    float* mrow = (float*)(smem + 34816);
    float* lrow = (float*)(smem + 35328);

    int t = threadIdx.x;
    int wv = t >> 6, lane = t & 63, quad = lane >> 4, l15 = lane & 15;
    int split = blockIdx.x;
    int bkv = blockIdx.y;
    int b = bkv >> 1, kv = bkv & 1;
    int off = offp[0];
    const float scl = 0.08838834764831845f;

    {
        int row = t >> 1, half = t & 1;
        int l = row & 15, hg = row >> 4;
        const float* qp = qkv + (size_t)(b * 16 + l) * LDQKV + (kv * 8 + hg) * 128 + half * 64;
        unsigned* Qu = (unsigned*)(Qs + row * 136 + half * 64);
        #pragma unroll
        for (int i = 0; i < 8; i++) {
            float4 v4 = *(const float4*)(qp + i * 8);
            float4 v5 = *(const float4*)(qp + i * 8 + 4);
            *(uint4*)(Qu + i * 4) = make_uint4(pk2(v4.x*scl, v4.y*scl), pk2(v4.z*scl, v4.w*scl),
                                               pk2(v5.x*scl, v5.y*scl), pk2(v5.z*scl, v5.w*scl));
        }
    }
    if (t < 128) { mrow[t] = -1e30f; lrow[t] = 0.f; }
    __syncthreads();

    s16x8 qf[2][4];
    #pragma unroll
    for (int mt = 0; mt < 2; mt++)
        #pragma unroll
        for (int ks = 0; ks < 4; ks++)
            qf[mt][ks] = *(const s16x8*)(Qs + (wv * 32 + mt * 16 + l15) * 136 + ks * 32 + quad * 8);

    f32x4 oacc[2][8];
    #pragma unroll
    for (int mt = 0; mt < 2; mt++)
        #pragma unroll
        for (int nt = 0; nt < 8; nt++)
            oacc[mt][nt] = (f32x4){0.f, 0.f, 0.f, 0.f};

    int s_begin = split * 128;
    int s_end = (split == NSPLIT - 1) ? STOT : s_begin + 128;

    for (int s0 = s_begin; s0 < s_end; s0 += 32) {
        int cs = min(32, s_end - s0);
        __syncthreads();
        {
            int key = t >> 3, dc = t & 7;
            int s = s0 + key; if (s > STOT - 1) s = STOT - 1;
            const float* kp = (s < S0C)
                ? ck + ((size_t)(b * 2 + kv) * S0C + s) * 128 + dc * 16
                : qkv + 2048 + (size_t)(b * 16 + (s - S0C)) * LDQKV + kv * 128 + dc * 16;
            float4 k0v = *(const float4*)(kp);
            float4 k1v = *(const float4*)(kp + 4);
            float4 k2v = *(const float4*)(kp + 8);
            float4 k3v = *(const float4*)(kp + 12);
            unsigned* Ku = (unsigned*)(Ks + key * 136 + dc * 16);
            *(uint4*)(Ku)     = make_uint4(pk2(k0v.x,k0v.y), pk2(k0v.z,k0v.w), pk2(k1v.x,k1v.y), pk2(k1v.z,k1v.w));
            *(uint4*)(Ku + 4) = make_uint4(pk2(k2v.x,k2v.y), pk2(k2v.z,k2v.w), pk2(k3v.x,k3v.y), pk2(k3v.z,k3v.w));
        }
        {
            int c = t & 31, dch = t >> 5;
            int s = s0 + c; if (s > STOT - 1) s = STOT - 1;
            const float* vp = (s < S0C)
                ? cv + ((size_t)(b * 2 + kv) * S0C + s) * 128 + dch * 16
                : qkv + 2304 + (size_t)(b * 16 + (s - S0C)) * LDQKV + kv * 128 + dch * 16;
            float vv[16];
            *(float4*)(vv)      = *(const float4*)(vp);
            *(float4*)(vv + 4)  = *(const float4*)(vp + 4);
            *(float4*)(vv + 8)  = *(const float4*)(vp + 8);
            *(float4*)(vv + 12) = *(const float4*)(vp + 12);
            #pragma unroll
            for (int j = 0; j < 16; j++)
                Vt[(dch * 16 + j) * 40 + c] = (short)f2bfu(vv[j]);
        }
        __syncthreads();
        f32x4 sa[2][2];
        sa[0][0] = (f32x4){0.f,0.f,0.f,0.f}; sa[0][1] = sa[0][0];
        sa[1][0] = sa[0][0];                 sa[1][1] = sa[0][0];
        #pragma unroll
        for (int ks = 0; ks < 4; ks++) {
            #pragma unroll
            for (int nt = 0; nt < 2; nt++) {
                s16x8 kf = *(const s16x8*)(Ks + (nt * 16 + l15) * 136 + ks * 32 + quad * 8);
                sa[0][nt] = MFMA16(qf[0][ks], kf, sa[0][nt]);
                sa[1][nt] = MFMA16(qf[1][ks], kf, sa[1][nt]);
            }
        }
        float alpha[2][4];
        #pragma unroll
        for (int mt = 0; mt < 2; mt++) {
            #pragma unroll
            for (int r = 0; r < 4; r++) {
                int row = wv * 32 + mt * 16 + quad * 4 + r;
                int ltok = row & 15;
                float s0v = sa[mt][0][r];
                float s1v = sa[mt][1][r];
                int g0 = s0 + l15, g1 = s0 + 16 + l15;
                bool ok0 = (l15 < cs) && (g0 <= off + ltok);
                bool ok1 = (16 + l15 < cs) && (g1 <= off + ltok);
                s0v = ok0 ? s0v : -3e38f;
                s1v = ok1 ? s1v : -3e38f;
                float mc = fmaxf(s0v, s1v);
                mc = fmaxf(mc, __shfl_xor(mc, 1));
                mc = fmaxf(mc, __shfl_xor(mc, 2));
                mc = fmaxf(mc, __shfl_xor(mc, 4));
                mc = fmaxf(mc, __shfl_xor(mc, 8));
                float mold = mrow[row];
                float mnew = fmaxf(mold, mc);
                float al = __expf(mold - mnew);
                float p0 = __expf(s0v - mnew);
                float p1 = __expf(s1v - mnew);
                float rs = p0 + p1;
                rs += __shfl_xor(rs, 1);
                rs += __shfl_xor(rs, 2);
                rs += __shfl_xor(rs, 4);
                rs += __shfl_xor(rs, 8);
                if (l15 == 0) { mrow[row] = mnew; lrow[row] = lrow[row] * al + rs; }
                alpha[mt][r] = al;
                Ps[row * 40 + l15] = (short)f2bfu(p0);
                Ps[row * 40 + 16 + l15] = (short)f2bfu(p1);
            }
        }
        #pragma unroll
        for (int mt = 0; mt < 2; mt++)
            #pragma unroll
            for (int nt = 0; nt < 8; nt++)
                #pragma unroll
                for (int r = 0; r < 4; r++)
                    oacc[mt][nt][r] *= alpha[mt][r];
        s16x8 pf0 = *(const s16x8*)(Ps + (wv * 32 + l15) * 40 + quad * 8);
        s16x8 pf1 = *(const s16x8*)(Ps + (wv * 32 + 16 + l15) * 40 + quad * 8);
        #pragma unroll
        for (int nt = 0; nt < 8; nt++) {
            s16x8 vf = *(const s16x8*)(Vt + (nt * 16 + l15) * 40 + quad * 8);
            oacc[0][nt] = MFMA16(pf0, vf, oacc[0][nt]);
            oacc[1][nt] = MFMA16(pf1, vf, oacc[1][nt]);
        }
    }

    __syncthreads();
    size_t obase = (size_t)(split * 16 + bkv) * 128;
    #pragma unroll
    for (int mt = 0; mt < 2; mt++)
        #pragma unroll
        for (int nt = 0; nt < 8; nt++)
            #pragma unroll
            for (int r = 0; r < 4; r++) {
                int row = wv * 32 + mt * 16 + quad * 4 + r;
                int d = nt * 16 + l15;
                Os[(obase + row) * 128 + d] = f2bfu(oacc[mt][nt][r]);
            }
    if (t < 128) { Mw[obase + t] = mrow[t]; Lw[obase + t] = lrow[t]; }
}

// ---------------- merge split partials -> bf16 fragged A (for o-proj, K=2048) ------
__global__ __launch_bounds__(256) void merge_kernel(const unsigned short* __restrict__ Os,
                                                    const float* __restrict__ Mw,
                                                    const float* __restrict__ Lw,
                                                    unsigned short* __restrict__ obf) {
    int blk = blockIdx.x;
    int bkv = blk >> 3, rg = blk & 7;
    int b = bkv >> 1, kv = bkv & 1;
    int t = threadIdx.x;
    int rowl = t >> 4;
    int row = rg * 16 + rowl;
    int dchunk = (t & 15) * 8;
    float M = -3e38f;
    for (int s = 0; s < NSPLIT; s++)
        M = fmaxf(M, Mw[((size_t)s * 16 + bkv) * 128 + row]);
    float denom = 0.f;
    float o[8];
    #pragma unroll
    for (int j = 0; j < 8; j++) o[j] = 0.f;
    for (int s = 0; s < NSPLIT; s++) {
        size_t base = ((size_t)s * 16 + bkv) * 128 + row;
        float w = __expf(Mw[base] - M);
        denom += Lw[base] * w;
        uint4 u = *(const uint4*)(Os + base * 128 + dchunk);
        o[0] += w * bf2f((unsigned short)(u.x & 0xffff));
        o[1] += w * bf2f((unsigned short)(u.x >> 16));
        o[2] += w * bf2f((unsigned short)(u.y & 0xffff));
        o[3] += w * bf2f((unsigned short)(u.y >> 16));
        o[4] += w * bf2f((unsigned short)(u.z & 0xffff));
        o[5] += w * bf2f((unsigned short)(u.z >> 16));
        o[6] += w * bf2f((unsigned short)(u.w & 0xffff));
        o[7] += w * bf2f((unsigned short)(u.w >> 16));
    }
    float inv = 1.f / denom;
    #pragma unroll
    for (int j = 0; j < 8; j++) o[j] *= inv;
    int m = b * 16 + rowl;                         // token row for o-proj A
    int e0 = (kv * 8 + rg) * 128 + dchunk;         // feature col, 8-aligned
    unsigned short* dst = obf + (e0 >> 5) * 4096 + ((e0 >> 3) & 3) * 1024 + m * 8;
    *(uint4*)dst = make_uint4(pk2(o[0], o[1]), pk2(o[2], o[3]),
                              pk2(o[4], o[5]), pk2(o[6], o[7]));
}

// ---------------- launch ----------------
extern "C" void kernel_launch(void* const* d_in, const int* in_sizes, int n_in,
                              void* d_out, int out_size, void* d_ws, size_t ws_size,
                              hipStream_t stream) {
    const float* x        = (const float*)d_in[0];
    const float* cache_k  = (const float*)d_in[1];
    const float* cache_v  = (const float*)d_in[2];
    const float* wq       = (const float*)d_in[3];
    const float* wk       = (const float*)d_in[4];
    const float* wv       = (const float*)d_in[5];
    const float* wo       = (const float*)d_in[6];
    const float* bq       = (const float*)d_in[7];
    const float* bk       = (const float*)d_in[8];
    const float* bv       = (const float*)d_in[9];
    const float* w_gate   = (const float*)d_in[10];
    const float* w_up     = (const float*)d_in[11];
    const float* w_down   = (const float*)d_in[12];
    const float* w_in_ln  = (const float*)d_in[13];
    const float* w_post_ln= (const float*)d_in[14];
    const int*   offp     = (const int*)d_in[15];
    float* out = (float*)d_out;

    float* ws = (float*)d_ws;
    float* qkvb = ws;                                   // 327680
    float* hb   = ws + 327680;                          // 262144 -> 589824
    unsigned short* xnf = (unsigned short*)(ws + 589824);   // 128*2048 bf16 = 131072 f
    unsigned short* hnf = (unsigned short*)(ws + 720896);   // 131072 f
    unsigned short* obf = (unsigned short*)(ws + 851968);   // 131072 f
    unsigned short* gbf = (unsigned short*)(ws + 983040);   // 128*5632 bf16 = 360448 f
    float* R = ws + 1343488;                            // P (<=2883584 f) / Os+Mw+Lw (4325376 f)
    float* P = R;
    unsigned short* Osw = (unsigned short*)R;
    float* Mw = R + 4194304;
    float* Lw = R + 4259840;                            // end: 5668864 f = 22.7 MB

    const int BIG = 1 << 30;

    // 1) input RMSNorm -> bf16 fragged
    rmsnorm_bf16<<<MM, 256, 0, stream>>>(x, w_in_ln, xnf);
    // 2) QKV: N=2560 (q|k|v), K=2048, SK=8 (Kc=256) -> 320 blocks
    gemm_stream<1><<<dim3(40, 8), 256, 0, stream>>>(xnf, wq, wk, wv, 2048, 2304, 2048, 256, P, LDQKV);
    reduce_qkv<<<320, 256, 0, stream>>>(P, bq, bk, bv, qkvb);
    rope_kernel<<<576, 256, 0, stream>>>(qkvb, offp);
    attn_kernel<<<dim3(NSPLIT, 16), 256, 0, stream>>>(qkvb, cache_k, cache_v, offp, Osw, Mw, Lw);
    merge_kernel<<<128, 256, 0, stream>>>(Osw, Mw, Lw, obf);
    // 3) O-proj: N=2048, K=2048, SK=8 -> 256 blocks
    gemm_stream<1><<<dim3(32, 8), 256, 0, stream>>>(obf, wo, wo, wo, BIG, BIG, 2048, 256, P, EE);
    reduce_res<<<256, 256, 0, stream>>>(P, x, hb);
    // 4) post RMSNorm -> bf16 fragged
    rmsnorm_bf16<<<MM, 256, 0, stream>>>(hb, w_post_ln, hnf);
    // 5) Gate|Up: N=11264, K=2048, NC=2 (128-col blocks), SK=2 (Kc=1024) -> 176 blocks
    gemm_stream<2><<<dim3(88, 2), 256, 0, stream>>>(hnf, w_gate, w_up, w_up, 5632, BIG, 2048, 1024, P, 11264);
    reduce_gateup<<<704, 256, 0, stream>>>(P, gbf);
    // 6) Down: N=2048, K=5632, SK=8 (Kc=704) -> 256 blocks
    gemm_stream<1><<<dim3(32, 8), 256, 0, stream>>>(gbf, w_down, w_down, w_down, BIG, BIG, 5632, 704, P, EE);
    reduce_res<<<256, 256, 0, stream>>>(P, hb, out);
}